// Round 6
// baseline (176.316 us; speedup 1.0000x reference)
//
#include <hip/hip_runtime.h>

#define N_  4096
#define D_  64
#define C_  256

typedef short bf16x8 __attribute__((ext_vector_type(8)));
typedef float f32x4  __attribute__((ext_vector_type(4)));

__device__ __forceinline__ unsigned short f2bf(float f) {
    union { float f; unsigned int i; } v; v.f = f;
    unsigned int r = v.i + 0x7fffu + ((v.i >> 16) & 1u);
    return (unsigned short)(r >> 16);
}

// ---------- fused prepass (no LDS, max occupancy) ----------
// blocks [0,256): q->bf16 ; [256,512): pg->bf16 ;
// blocks [512, 512+2048): v -> vt2 in MFMA-B-frag order, ONE WAVE PER FRAGMENT.
//   frag f = ((b*32 + jt)*16 + cb)*4 + ks  (512 shorts, contiguous 1KB)
//   vt2[f*512 + lane*8 + e] = v[b][jt*128 + ks*32 + (lane>>4)*8 + e][cb*16 + (lane&15)]
__global__ void prepass_kernel(const float* __restrict__ xq,
                               const float* __restrict__ pg,
                               const float* __restrict__ xv,
                               unsigned short* __restrict__ qbf,
                               unsigned short* __restrict__ pgbf,
                               unsigned short* __restrict__ vt2) {
    const int bid = blockIdx.x;
    const int t   = threadIdx.x;
    if (bid < 512) {
        const float* src = (bid < 256) ? xq : pg;
        unsigned short* dst = (bid < 256) ? qbf : pgbf;
        const int base = (bid & 255) * 1024 + t;
#pragma unroll
        for (int it = 0; it < 4; ++it) {
            const int i = base + it * 256;
            float4 v = ((const float4*)src)[i];
            ushort4 o;
            o.x = f2bf(v.x); o.y = f2bf(v.y); o.z = f2bf(v.z); o.w = f2bf(v.w);
            ((ushort4*)dst)[i] = o;
        }
        return;
    }
    // V fragment emit: 4 waves/block, one frag per wave
    const int lane = t & 63;
    const int w    = t >> 6;
    const int l15  = lane & 15;
    const int quad = lane >> 4;
    const int f    = (bid - 512) * 4 + w;        // 0..8191
    const int b    = f >> 11;
    const int jt   = (f >> 6) & 31;
    const int cb   = (f >> 2) & 15;
    const int ks   = f & 3;
    const int c    = cb * 16 + l15;
    const int jb   = jt * 128 + ks * 32 + quad * 8;
    const float* src = xv + ((size_t)b * N_ + jb) * C_ + c;
    float v0 = src[0 * C_], v1 = src[1 * C_], v2 = src[2 * C_], v3 = src[3 * C_];
    float v4 = src[4 * C_], v5 = src[5 * C_], v6 = src[6 * C_], v7 = src[7 * C_];
    uint4 o;
    o.x = (unsigned)f2bf(v0) | ((unsigned)f2bf(v1) << 16);
    o.y = (unsigned)f2bf(v2) | ((unsigned)f2bf(v3) << 16);
    o.z = (unsigned)f2bf(v4) | ((unsigned)f2bf(v5) << 16);
    o.w = (unsigned)f2bf(v6) | ((unsigned)f2bf(v7) << 16);
    *(uint4*)(vt2 + (size_t)f * 512 + lane * 8) = o;
}

// ---------- main: 512 blocks x 256 thr (4 waves), 64 rows x 128-ch half ----------
// 2 INDEPENDENT blocks/CU (ch split): when one block sits at its barrier, the
// other's MFMA/LDS work runs -> covers the barrier-lockstep latency that
// bounded R3. S (and exp) duplicated per block: S is 1/5 of MFMA work and the
// matrix/TRANS pipes are <30% busy, so duplication is cheap.
// Wave w = (jh=w>>1: j-half = 2 K-slices, ch2=w&1: 64-ch half of block's 128).
//   -> 8 ds_read_b128 of P + 32 PV MFMA per wave per jt; V frag read once/block.
// Register budget: oacc[4][4]=64 + pgf 32 + qf dbuf 32 + vf 32 + transients
//   ~= 210 VGPR; __launch_bounds__(256,2) -> 2 waves/SIMD -> 256-reg cap: FITS
//   (R4/R5 spilled at the 128 cap of (512,2)).
__global__ __launch_bounds__(256, 2) void attn_main(
    const float* __restrict__ g,  const float* __restrict__ x,
    const float* __restrict__ kk, float* __restrict__ out,
    const unsigned short* __restrict__ qbf,
    const unsigned short* __restrict__ pgbf,
    const unsigned short* __restrict__ vt2)
{
    // loop: pb0/pb1 = 2 x 16KB P buffers (XOR-swizzled) at smem[0..32768)
    // merge: 2 regions of [64][68] f32 (17408 B) at 0 / 17408, reused space
    __shared__ __align__(16) unsigned char smem[34816];
    __shared__ float s_l[64];

    const int t    = threadIdx.x;
    const int lane = t & 63;
    const int w    = t >> 6;            // 0..3
    const int l15  = lane & 15;
    const int quad = lane >> 4;
    const int swz  = (l15 & 7) << 4;
    const int jh   = w >> 1;            // j-half 0..1 (2 K-slices)
    const int ch2  = w & 1;             // 64-ch half of block's 128

    const int bid  = blockIdx.x;
    const int b    = bid & 3;           // batch pinned to 2 XCDs
    const int cblk = (bid >> 2) & 1;    // block's 128-ch half (0/1) - other XCD
    const int rg   = bid >> 3;          // 0..63
    const int i0   = rg * 64;
    const int c0   = cblk * 128;
    const size_t rowbase = (size_t)b * N_ + i0;

    if (t < 64) s_l[t] = 0.f;

    // ---- g passthrough: 64 rows x this block's 128 ch ----
#pragma unroll
    for (int it = 0; it < 8; ++it) {
        const int idx = it * 256 + t;   // 0..2047
        const int row = idx >> 5;       // 32 float4 per row
        const int cq  = idx & 31;
        const int c   = c0 + cq * 4;
        const float4 gv = *(const float4*)(g + (rowbase + row) * C_ + c);
        *(float4*)(out + (rowbase + row) * (2 * C_) + C_ + c) = gv;
    }

    // ---- pg B-frags: 4 i-tiles x 2 K-slices, persistent ----
    bf16x8 pgf[4][2];
#pragma unroll
    for (int nt = 0; nt < 4; ++nt)
#pragma unroll
        for (int ks = 0; ks < 2; ++ks)
            pgf[nt][ks] = *(const bf16x8*)(pgbf +
                (rowbase + nt * 16 + l15) * D_ + ks * 32 + quad * 8);

    f32x4 oacc[4][4];                   // [mt][ct]: 64 rows x wave's 64 ch
#pragma unroll
    for (int mt = 0; mt < 4; ++mt)
#pragma unroll
        for (int ct = 0; ct < 4; ++ct)
            oacc[mt][ct] = (f32x4){0.f, 0.f, 0.f, 0.f};
    float ls[4] = {0.f, 0.f, 0.f, 0.f};

    const unsigned short* qb  = qbf + (size_t)b * N_ * D_;
    const unsigned short* vtb = vt2 + (size_t)b * N_ * C_;
    unsigned short* const pb0 = (unsigned short*)smem;
    unsigned short* const pb1 = (unsigned short*)(smem + 16384);

    // q A-frags for the wave's TWO 16-j strips (strips w and w+4)
    auto load_q = [&](bf16x8 (&qf)[2][2], int jt) {
        const int jtc = (jt < 31) ? jt : 31;
#pragma unroll
        for (int s = 0; s < 2; ++s)
#pragma unroll
            for (int ks = 0; ks < 2; ++ks)
                qf[s][ks] = *(const bf16x8*)(qb +
                    (size_t)(jtc * 128 + (w + s * 4) * 16 + l15) * D_ +
                    ks * 32 + quad * 8);
    };
    // V frags: cb = cblk*8 + ch2*4 + ct, ks = jh*2 + ks2 (each frag -> ONE wave)
    auto load_v = [&](bf16x8 (&vf)[2][4], int jt) {
#pragma unroll
        for (int ks2 = 0; ks2 < 2; ++ks2)
#pragma unroll
            for (int ct = 0; ct < 4; ++ct)
                vf[ks2][ct] = *(const bf16x8*)(vtb +
                    ((size_t)(jt * 16 + cblk * 8 + ch2 * 4 + ct) * 4 +
                     (jh * 2 + ks2)) * 512 + (size_t)lane * 8);
    };
    // S for one jt (2 strips): 16 MFMA -> 32 exp -> 8x ds_write_b64
    auto s_step = [&](const bf16x8 (&qf)[2][2], unsigned short* pbuf) {
#pragma unroll
        for (int s = 0; s < 2; ++s) {
            const int strip = w + s * 4;
            f32x4 sacc[4];
#pragma unroll
            for (int nt = 0; nt < 4; ++nt) sacc[nt] = (f32x4){0.f,0.f,0.f,0.f};
#pragma unroll
            for (int ks = 0; ks < 2; ++ks)
#pragma unroll
                for (int nt = 0; nt < 4; ++nt)
                    sacc[nt] = __builtin_amdgcn_mfma_f32_16x16x32_bf16(
                        qf[s][ks], pgf[nt][ks], sacc[nt], 0, 0, 0);
#pragma unroll
            for (int nt = 0; nt < 4; ++nt) {
                const float p0 = __expf(sacc[nt][0]);
                const float p1 = __expf(sacc[nt][1]);
                const float p2 = __expf(sacc[nt][2]);
                const float p3 = __expf(sacc[nt][3]);
                ls[nt] += (p0 + p1) + (p2 + p3);
                ushort4 pk;
                pk.x = f2bf(p0); pk.y = f2bf(p1); pk.z = f2bf(p2); pk.w = f2bf(p3);
                const int wb = ((nt * 16 + l15) * 256 +
                                (strip * 16 + quad * 4) * 2) ^ swz;
                *(ushort4*)((char*)pbuf + wb) = pk;
            }
        }
    };
    // PV for one jt: 8x ds_read_b128 (wave's j-half) + 32 MFMA
    auto pv_step = [&](const bf16x8 (&vf)[2][4], const unsigned short* pbuf) {
#pragma unroll
        for (int ks2 = 0; ks2 < 2; ++ks2) {
            const int ks = jh * 2 + ks2;
            bf16x8 pa[4];
#pragma unroll
            for (int mt = 0; mt < 4; ++mt) {
                const int rb = ((mt * 16 + l15) * 256 + (ks * 32 + quad * 8) * 2) ^ swz;
                pa[mt] = *(const bf16x8*)((const char*)pbuf + rb);
            }
            __builtin_amdgcn_s_setprio(1);
#pragma unroll
            for (int ct = 0; ct < 4; ++ct)
#pragma unroll
                for (int mt = 0; mt < 4; ++mt)
                    oacc[mt][ct] = __builtin_amdgcn_mfma_f32_16x16x32_bf16(
                        pa[mt], vf[ks2][ct], oacc[mt][ct], 0, 0, 0);
            __builtin_amdgcn_s_setprio(0);
        }
    };

    bf16x8 qfA[2][2], qfB[2][2], vf[2][4];

    // ---- prologue: S(0) -> buf0 ----
    load_q(qfA, 0);
    s_step(qfA, pb0);
    load_q(qfB, 1);
    __syncthreads();

    // ---- pipelined main loop: 2 jt per iteration, 1 barrier per jt ----
#pragma unroll 1
    for (int jtp = 0; jtp < 15; ++jtp) {
        const int p = 2 * jtp;
        // even phase p: PV(p) + S(p+1)
        load_v(vf, p);
        load_q(qfA, p + 2);
        s_step(qfB, pb1);
        pv_step(vf, pb0);
        __syncthreads();
        // odd phase p+1: PV(p+1) + S(p+2)
        load_v(vf, p + 1);
        load_q(qfB, p + 3);
        s_step(qfA, pb0);
        pv_step(vf, pb1);
        __syncthreads();
    }
    // tail: phase 30 then 31
    load_v(vf, 30);
    s_step(qfB, pb1);               // S(31) -> buf1
    pv_step(vf, pb0);               // PV(30)
    __syncthreads();
    load_v(vf, 31);
    pv_step(vf, pb1);               // PV(31)

    // ---- l reduction: lane holds i=nt*16+l15; sum quads then 4 waves ----
#pragma unroll
    for (int nt = 0; nt < 4; ++nt) {
        float s = ls[nt];
        s += __shfl_xor(s, 16);
        s += __shfl_xor(s, 32);
        if (lane < 16) atomicAdd(&s_l[nt * 16 + lane], s);
    }
    __syncthreads();   // P buffers dead; smem reused for merge below

    // ---- O merge over jh (2 partials per (row, ch)): jh=1 writes, jh=0 adds ----
    {
        float* Rg = (float*)(smem + (size_t)ch2 * 17408);   // [64][68] f32
        if (jh == 1) {
#pragma unroll
            for (int mt = 0; mt < 4; ++mt)
#pragma unroll
                for (int ct = 0; ct < 4; ++ct)
#pragma unroll
                    for (int r = 0; r < 4; ++r)
                        Rg[(mt * 16 + quad * 4 + r) * 68 + ct * 16 + l15] =
                            oacc[mt][ct][r];
        }
        __syncthreads();
        if (jh == 0) {
#pragma unroll
            for (int mt = 0; mt < 4; ++mt)
#pragma unroll
                for (int ct = 0; ct < 4; ++ct)
#pragma unroll
                    for (int r = 0; r < 4; ++r) {
                        const int idx = (mt * 16 + quad * 4 + r) * 68 + ct * 16 + l15;
                        Rg[idx] += oacc[mt][ct][r];
                    }
        }
        __syncthreads();
    }

    // ---- epilogue: vectorized, 2048 float4 over 256 threads ----
    const float kval = kk[0];
#pragma unroll
    for (int it = 0; it < 8; ++it) {
        const int idx = it * 256 + t;       // 0..2047
        const int row = idx >> 5;           // 32 float4-cols per row (128 ch)
        const int cq  = idx & 31;
        const float* Rg = (const float*)(smem + (size_t)(cq >> 4) * 17408);
        const f32x4 ov = *(const f32x4*)&Rg[row * 68 + (cq & 15) * 4];
        const float linv = 1.f / s_l[row];
        const size_t rr = rowbase + row;
        const int c = c0 + cq * 4;
        const float4 xv4 = *(const float4*)(x + rr * C_ + c);
        float4 o4;
        o4.x = kval * (ov[0] * linv) + xv4.x;
        o4.y = kval * (ov[1] * linv) + xv4.y;
        o4.z = kval * (ov[2] * linv) + xv4.z;
        o4.w = kval * (ov[3] * linv) + xv4.w;
        *(float4*)(out + rr * (2 * C_) + c) = o4;
    }
}

// ---------- fallback (round-2 vector kernel) if workspace too small ----------
#define ROWS 4
#define FNT  256
__global__ __launch_bounds__(FNT, 2) void attn_fallback(
    const float* __restrict__ g, const float* __restrict__ x,
    const float* __restrict__ xq, const float* __restrict__ pg,
    const float* __restrict__ xv, const float* __restrict__ kk,
    float* __restrict__ out)
{
    __shared__ __align__(16) float s_pg[ROWS][D_];
    __shared__ __align__(16) float s_sc[N_ * ROWS];
    __shared__ float s_rmax[4][ROWS];
    __shared__ float s_rsum[4][ROWS];

    const int t = threadIdx.x, lane = t & 63, w = t >> 6, blk = blockIdx.x;
    const int b = blk >> 10, i0 = (blk & 1023) * ROWS;
    const size_t rowbase = (size_t)b * N_ + i0;
    {
        const int r = t >> 6, cc = (t & 63) * 4;
        const float4 gv = *(const float4*)(g + (rowbase + r) * C_ + cc);
        *(float4*)(out + (rowbase + r) * (2 * C_) + C_ + cc) = gv;
    }
    { const int r = t >> 6, d = t & 63; s_pg[r][d] = pg[(rowbase + r) * D_ + d]; }
    __syncthreads();
    const float* qb = xq + (size_t)b * N_ * D_;
    float lmax[ROWS];
#pragma unroll
    for (int r = 0; r < ROWS; ++r) lmax[r] = -1e30f;
    for (int jj = 0; jj < N_ / FNT; ++jj) {
        const int j = t + jj * FNT;
        const float4* q4p = (const float4*)(qb + (size_t)j * D_);
        float s[ROWS] = {0.f, 0.f, 0.f, 0.f};
#pragma unroll
        for (int u = 0; u < D_ / 8; ++u) {
            const float4 qa = q4p[u * 2], qc = q4p[u * 2 + 1];
#pragma unroll
            for (int r = 0; r < ROWS; ++r) {
                const float4 pa = *(const float4*)&s_pg[r][u * 8];
                const float4 pb = *(const float4*)&s_pg[r][u * 8 + 4];
                s[r] += qa.x * pa.x + qa.y * pa.y + qa.z * pa.z + qa.w * pa.w
                      + qc.x * pb.x + qc.y * pb.y + qc.z * pb.z + qc.w * pb.w;
            }
        }
        *(float4*)&s_sc[j * ROWS] = make_float4(s[0], s[1], s[2], s[3]);
#pragma unroll
        for (int r = 0; r < ROWS; ++r) lmax[r] = fmaxf(lmax[r], s[r]);
    }
#pragma unroll
    for (int r = 0; r < ROWS; ++r) {
        float m = lmax[r];
        for (int o = 32; o > 0; o >>= 1) m = fmaxf(m, __shfl_down(m, o));
        if (lane == 0) s_rmax[w][r] = m;
    }
    __syncthreads();
    float bmax[ROWS];
#pragma unroll
    for (int r = 0; r < ROWS; ++r)
        bmax[r] = fmaxf(fmaxf(s_rmax[0][r], s_rmax[1][r]), fmaxf(s_rmax[2][r], s_rmax[3][r]));
    float lsum[ROWS] = {0.f, 0.f, 0.f, 0.f};
    for (int jj = 0; jj < N_ / FNT; ++jj) {
        const int j = t + jj * FNT;
        float4 s4 = *(const float4*)&s_sc[j * ROWS];
        s4.x = __expf(s4.x - bmax[0]); s4.y = __expf(s4.y - bmax[1]);
        s4.z = __expf(s4.z - bmax[2]); s4.w = __expf(s4.w - bmax[3]);
        *(float4*)&s_sc[j * ROWS] = s4;
        lsum[0] += s4.x; lsum[1] += s4.y; lsum[2] += s4.z; lsum[3] += s4.w;
    }
#pragma unroll
    for (int r = 0; r < ROWS; ++r) {
        float sm = lsum[r];
        for (int o = 32; o > 0; o >>= 1) sm += __shfl_down(sm, o);
        if (lane == 0) s_rsum[w][r] = sm;
    }
    __syncthreads();
    float rinv[ROWS];
#pragma unroll
    for (int r = 0; r < ROWS; ++r)
        rinv[r] = 1.f / (s_rsum[0][r] + s_rsum[1][r] + s_rsum[2][r] + s_rsum[3][r]);
    const int jg = lane >> 4;
    const int c0 = (w * 16 + (lane & 15)) * 4;
    const float* vb = xv + (size_t)b * N_ * C_;
    float acc[ROWS][4];
#pragma unroll
    for (int r = 0; r < ROWS; ++r)
#pragma unroll
        for (int q = 0; q < 4; ++q) acc[r][q] = 0.f;
#pragma unroll 4
    for (int jj = 0; jj < N_ / 4; ++jj) {
        const int j = jj * 4 + jg;
        const float4 p4 = *(const float4*)&s_sc[j * ROWS];
        const float4 v4 = *(const float4*)(vb + (size_t)j * C_ + c0);
        acc[0][0] += p4.x * v4.x; acc[0][1] += p4.x * v4.y; acc[0][2] += p4.x * v4.z; acc[0][3] += p4.x * v4.w;
        acc[1][0] += p4.y * v4.x; acc[1][1] += p4.y * v4.y; acc[1][2] += p4.y * v4.z; acc[1][3] += p4.y * v4.w;
        acc[2][0] += p4.z * v4.x; acc[2][1] += p4.z * v4.y; acc[2][2] += p4.z * v4.z; acc[2][3] += p4.z * v4.w;
        acc[3][0] += p4.w * v4.x; acc[3][1] += p4.w * v4.y; acc[3][2] += p4.w * v4.z; acc[3][3] += p4.w * v4.w;
    }
#pragma unroll
    for (int r = 0; r < ROWS; ++r)
#pragma unroll
        for (int q = 0; q < 4; ++q) {
            acc[r][q] += __shfl_xor(acc[r][q], 16);
            acc[r][q] += __shfl_xor(acc[r][q], 32);
        }
    const float kval = kk[0];
    if (lane < 16) {
        const int c = (w * 16 + lane) * 4;
#pragma unroll
        for (int r = 0; r < ROWS; ++r) {
            const float4 xv4 = *(const float4*)(x + (rowbase + r) * C_ + c);
            float4 ov;
            ov.x = kval * (acc[r][0] * rinv[r]) + xv4.x;
            ov.y = kval * (acc[r][1] * rinv[r]) + xv4.y;
            ov.z = kval * (acc[r][2] * rinv[r]) + xv4.z;
            ov.w = kval * (acc[r][3] * rinv[r]) + xv4.w;
            *(float4*)(out + (rowbase + r) * (2 * C_) + c) = ov;
        }
    }
}

extern "C" void kernel_launch(void* const* d_in, const int* in_sizes, int n_in,
                              void* d_out, int out_size, void* d_ws, size_t ws_size,
                              hipStream_t stream) {
    const float* g  = (const float*)d_in[0];
    const float* x  = (const float*)d_in[1];
    const float* xq = (const float*)d_in[2];
    const float* pg = (const float*)d_in[3];
    const float* xv = (const float*)d_in[4];
    const float* kk = (const float*)d_in[5];
    float* out = (float*)d_out;

    const int B = in_sizes[0] / (N_ * C_);   // 4
    const size_t qn = (size_t)B * N_ * D_;
    const size_t vn = (size_t)B * N_ * C_;
    const size_t need = (2 * qn + vn) * sizeof(unsigned short);

    if (B != 4 || ws_size < need) {
        attn_fallback<<<dim3(B * (N_ / ROWS)), FNT, 0, stream>>>(g, x, xq, pg, xv, kk, out);
        return;
    }

    unsigned short* qbf  = (unsigned short*)d_ws;
    unsigned short* pgbf = qbf + qn;
    unsigned short* vt2  = pgbf + qn;

    prepass_kernel<<<dim3(512 + B * 512), 256, 0, stream>>>(xq, pg, xv, qbf, pgbf, vt2);
    attn_main<<<dim3(B * (N_ / 64) * 2), 256, 0, stream>>>(g, x, kk, out, qbf, pgbf, vt2);
}

// Round 8
// 153.554 us; speedup vs baseline: 1.1482x; 1.1482x over previous
//
#include <hip/hip_runtime.h>

#define N_  4096
#define D_  64
#define C_  256

typedef short bf16x8 __attribute__((ext_vector_type(8)));
typedef float f32x4  __attribute__((ext_vector_type(4)));

__device__ __forceinline__ unsigned short f2bf(float f) {
    union { float f; unsigned int i; } v; v.f = f;
    unsigned int r = v.i + 0x7fffu + ((v.i >> 16) & 1u);
    return (unsigned short)(r >> 16);
}

// ---------- fused prepass ----------
// blocks [0,512): q->bf16 / pg->bf16 (coalesced float4->ushort4, unchanged).
// blocks [512, 512+512): V -> vt2 in MFMA-B-frag order via LDS-staged
//   coalesced transpose. Block = (b, jt, cq=64-ch quarter):
//   stage v[b][jt*128..+127][cq*64..+63] with float4 reads (fully coalesced)
//   -> bf16 LDS [128][66] (stride 66 shorts: b32 staging writes are
//   conflict-free; frag u16 reads hit 32 distinct banks) -> each wave (=ks)
//   emits 4 frags with coalesced 16B stores.
// Frag layout (bit-identical to consumer's expectation):
//   f = ((b*32 + jt)*16 + cb)*4 + ks
//   vt2[f*512 + lane*8 + e] = v[b][jt*128 + ks*32 + (lane>>4)*8 + e][cb*16 + (lane&15)]
__global__ void prepass_kernel(const float* __restrict__ xq,
                               const float* __restrict__ pg,
                               const float* __restrict__ xv,
                               unsigned short* __restrict__ qbf,
                               unsigned short* __restrict__ pgbf,
                               unsigned short* __restrict__ vt2) {
    const int bid = blockIdx.x;
    const int t   = threadIdx.x;
    if (bid < 512) {
        const float* src = (bid < 256) ? xq : pg;
        unsigned short* dst = (bid < 256) ? qbf : pgbf;
        const int base = (bid & 255) * 1024 + t;
#pragma unroll
        for (int it = 0; it < 4; ++it) {
            const int i = base + it * 256;
            float4 v = ((const float4*)src)[i];
            ushort4 o;
            o.x = f2bf(v.x); o.y = f2bf(v.y); o.z = f2bf(v.z); o.w = f2bf(v.w);
            ((ushort4*)dst)[i] = o;
        }
        return;
    }

    // ---- V staging path ----
    __shared__ unsigned short vs[128 * 66];   // 16896 B
    const int vb   = bid - 512;       // 0..511
    const int b    = vb >> 7;         // batch
    const int rem  = vb & 127;
    const int jt   = rem >> 2;        // 0..31
    const int cq   = rem & 3;         // 64-ch quarter
    const int lane = t & 63;
    const int w    = t >> 6;          // wave = ks
    const int l15  = lane & 15;
    const int quad = lane >> 4;

    // stage: 8 passes x (1 coalesced float4 read + 2 b32 LDS writes)
    {
        const int jr = t >> 4;                // 0..15 (row within pass)
        const int c0 = (t & 15) * 4;          // 0..60
        const float* src = xv + ((size_t)b * N_ + jt * 128 + jr) * C_ + cq * 64 + c0;
        unsigned short* dst = &vs[jr * 66 + c0];
#pragma unroll
        for (int p = 0; p < 8; ++p) {
            const float4 v4 = *(const float4*)(src + (size_t)p * 16 * C_);
            const unsigned int lo = (unsigned)f2bf(v4.x) | ((unsigned)f2bf(v4.y) << 16);
            const unsigned int hi = (unsigned)f2bf(v4.z) | ((unsigned)f2bf(v4.w) << 16);
            *(unsigned int*)(dst + p * 16 * 66)     = lo;   // 4B-aligned: (jr*66+c0)*2 % 4 == 0
            *(unsigned int*)(dst + p * 16 * 66 + 2) = hi;
        }
    }
    __syncthreads();

    // emit: wave w = K-slice ks; 4 frags (cb_local 0..3)
    const int ks = w;
#pragma unroll
    for (int cb = 0; cb < 4; ++cb) {
        const unsigned short* pr = &vs[(ks * 32 + quad * 8) * 66 + cb * 16 + l15];
        const unsigned short e0 = pr[0 * 66], e1 = pr[1 * 66];
        const unsigned short e2 = pr[2 * 66], e3 = pr[3 * 66];
        const unsigned short e4 = pr[4 * 66], e5 = pr[5 * 66];
        const unsigned short e6 = pr[6 * 66], e7 = pr[7 * 66];
        uint4 o;
        o.x = (unsigned)e0 | ((unsigned)e1 << 16);
        o.y = (unsigned)e2 | ((unsigned)e3 << 16);
        o.z = (unsigned)e4 | ((unsigned)e5 << 16);
        o.w = (unsigned)e6 | ((unsigned)e7 << 16);
        const int f = ((b * 32 + jt) * 16 + (cq * 4 + cb)) * 4 + ks;
        *(uint4*)(vt2 + (size_t)f * 512 + lane * 8) = o;
    }
}

// ---------- main: 256 blocks x 512 thr (8 waves), M=64, j-tile 128 ----------
// R3 VERBATIM (proven: passed, 66 us, 116 VGPR no spill).
// Swapped-S: S = mfma(A=q_strip, B=pg) -> lane holds S[j=strip+4q+r][i=nt*16+l15]
//   -> 4 consecutive j per lane -> ONE ds_write_b64 per nt.
// P stored TRANSPOSED [i][j_local] in [64][128]-short tile with XOR swizzle
//   byte ^= (i&7)<<4. jt loop software-pipelined (unroll-2, static dbuf).
__global__ __launch_bounds__(512, 2) void attn_main(
    const float* __restrict__ g,  const float* __restrict__ x,
    const float* __restrict__ kk, float* __restrict__ out,
    const unsigned short* __restrict__ qbf,
    const unsigned short* __restrict__ pgbf,
    const unsigned short* __restrict__ vt2)
{
    __shared__ unsigned short p_lds[2][64 * 128];   // 32 KB, XOR-swizzled
    __shared__ float s_l[64];

    const int t    = threadIdx.x;
    const int lane = t & 63;
    const int w    = t >> 6;
    const int l15  = lane & 15;
    const int quad = lane >> 4;
    const int swz  = (l15 & 7) << 4;

    const int bid = blockIdx.x;
    const int b   = bid & 3;
    const int rg  = bid >> 2;
    const int i0  = rg * 64;
    const size_t rowbase = (size_t)b * N_ + i0;

    if (t < 64) s_l[t] = 0.f;

    // ---- g passthrough: 64 rows x 256 ch ----
#pragma unroll
    for (int it = 0; it < 8; ++it) {
        const int row = it * 8 + w;
        const int c4  = lane * 4;
        const float4 gv = *(const float4*)(g + (rowbase + row) * C_ + c4);
        *(float4*)(out + (rowbase + row) * (2 * C_) + C_ + c4) = gv;
    }

    // ---- pg B-frags: 4 i-tiles x 2 K-slices, persistent ----
    bf16x8 pgf[4][2];
#pragma unroll
    for (int nt = 0; nt < 4; ++nt)
#pragma unroll
        for (int ks = 0; ks < 2; ++ks)
            pgf[nt][ks] = *(const bf16x8*)(pgbf +
                (rowbase + nt * 16 + l15) * D_ + ks * 32 + quad * 8);

    f32x4 oacc[4][2];
#pragma unroll
    for (int mt = 0; mt < 4; ++mt) { oacc[mt][0] = (f32x4){0.f,0.f,0.f,0.f};
                                     oacc[mt][1] = (f32x4){0.f,0.f,0.f,0.f}; }
    float ls[4] = {0.f, 0.f, 0.f, 0.f};

    const unsigned short* qb  = qbf + (size_t)b * N_ * D_;
    const unsigned short* vtb = vt2 + (size_t)b * N_ * C_;
    unsigned short* const pb0 = &p_lds[0][0];
    unsigned short* const pb1 = &p_lds[1][0];

    auto load_q = [&](bf16x8 (&qf)[2], int jt) {
#pragma unroll
        for (int ks = 0; ks < 2; ++ks)
            qf[ks] = *(const bf16x8*)(qb +
                (size_t)(jt * 128 + w * 16 + l15) * D_ + ks * 32 + quad * 8);
    };
    auto load_v = [&](bf16x8 (&vf)[4][2], int jt) {
        const unsigned short* tbase = vtb + (size_t)jt * 32768;
#pragma unroll
        for (int ks = 0; ks < 4; ++ks)
#pragma unroll
            for (int ctl = 0; ctl < 2; ++ctl)
                vf[ks][ctl] = *(const bf16x8*)(tbase +
                    (size_t)(((w * 2 + ctl) * 4) + ks) * 512 + lane * 8);
    };
    auto s_step = [&](const bf16x8 (&qf)[2], unsigned short* pbuf) {
        f32x4 sacc[4];
#pragma unroll
        for (int nt = 0; nt < 4; ++nt) sacc[nt] = (f32x4){0.f,0.f,0.f,0.f};
#pragma unroll
        for (int ks = 0; ks < 2; ++ks)
#pragma unroll
            for (int nt = 0; nt < 4; ++nt)
                sacc[nt] = __builtin_amdgcn_mfma_f32_16x16x32_bf16(
                    qf[ks], pgf[nt][ks], sacc[nt], 0, 0, 0);
#pragma unroll
        for (int nt = 0; nt < 4; ++nt) {
            const float p0 = __expf(sacc[nt][0]);
            const float p1 = __expf(sacc[nt][1]);
            const float p2 = __expf(sacc[nt][2]);
            const float p3 = __expf(sacc[nt][3]);
            ls[nt] += (p0 + p1) + (p2 + p3);
            ushort4 pk;
            pk.x = f2bf(p0); pk.y = f2bf(p1); pk.z = f2bf(p2); pk.w = f2bf(p3);
            const int wb = ((nt * 16 + l15) * 256 + (w * 16 + quad * 4) * 2) ^ swz;
            *(ushort4*)((char*)pbuf + wb) = pk;
        }
    };
    auto pv_step = [&](const bf16x8 (&vf)[4][2], const unsigned short* pbuf) {
#pragma unroll
        for (int ks = 0; ks < 4; ++ks) {
            bf16x8 pa[4];
#pragma unroll
            for (int mt = 0; mt < 4; ++mt) {
                const int rb = ((mt * 16 + l15) * 256 + (ks * 32 + quad * 8) * 2) ^ swz;
                pa[mt] = *(const bf16x8*)((const char*)pbuf + rb);
            }
#pragma unroll
            for (int mt = 0; mt < 4; ++mt) {
                oacc[mt][0] = __builtin_amdgcn_mfma_f32_16x16x32_bf16(pa[mt], vf[ks][0], oacc[mt][0], 0, 0, 0);
                oacc[mt][1] = __builtin_amdgcn_mfma_f32_16x16x32_bf16(pa[mt], vf[ks][1], oacc[mt][1], 0, 0, 0);
            }
        }
    };

    bf16x8 qfA[2], qfB[2], vfA[4][2], vfB[4][2];

    // ---- prologue: S(0) -> buf0 ----
    load_q(qfA, 0);
    load_v(vfA, 0);
    s_step(qfA, pb0);
    load_q(qfB, 1);
    __syncthreads();

    // ---- pipelined main loop: 2 jt per iteration ----
#pragma unroll 1
    for (int jtp = 0; jtp < 15; ++jtp) {
        const int jt0 = 2 * jtp;
        load_v(vfB, jt0 + 1);
        load_q(qfA, jt0 + 2);
        s_step(qfB, pb1);
        pv_step(vfA, pb0);
        __syncthreads();
        load_v(vfA, jt0 + 2);
        load_q(qfB, jt0 + 3);
        s_step(qfA, pb0);
        pv_step(vfB, pb1);
        __syncthreads();
    }
    // tail: jt=30 then jt=31
    load_v(vfB, 31);
    s_step(qfB, pb1);
    pv_step(vfA, pb0);
    __syncthreads();
    pv_step(vfB, pb1);

    // ---- l reduction ----
#pragma unroll
    for (int nt = 0; nt < 4; ++nt) {
        float s = ls[nt];
        s += __shfl_xor(s, 16);
        s += __shfl_xor(s, 32);
        if (lane < 16) atomicAdd(&s_l[nt * 16 + lane], s);
    }
    __syncthreads();

    // ---- epilogue: wave owns all 64 rows x its 32-ch octant ----
    const float kval = kk[0];
#pragma unroll
    for (int mt = 0; mt < 4; ++mt)
#pragma unroll
        for (int r = 0; r < 4; ++r) {
            const int m = mt * 16 + quad * 4 + r;
            const float linv = 1.f / s_l[m];
            const size_t row = rowbase + m;
#pragma unroll
            for (int ctl = 0; ctl < 2; ++ctl) {
                const int c = w * 32 + ctl * 16 + l15;
                out[row * (2 * C_) + c] = kval * (oacc[mt][ctl][r] * linv) + x[row * C_ + c];
            }
        }
}

// ---------- fallback (round-2 vector kernel) if workspace too small ----------
#define ROWS 4
#define FNT  256
__global__ __launch_bounds__(FNT, 2) void attn_fallback(
    const float* __restrict__ g, const float* __restrict__ x,
    const float* __restrict__ xq, const float* __restrict__ pg,
    const float* __restrict__ xv, const float* __restrict__ kk,
    float* __restrict__ out)
{
    __shared__ __align__(16) float s_pg[ROWS][D_];
    __shared__ __align__(16) float s_sc[N_ * ROWS];
    __shared__ float s_rmax[4][ROWS];
    __shared__ float s_rsum[4][ROWS];

    const int t = threadIdx.x, lane = t & 63, w = t >> 6, blk = blockIdx.x;
    const int b = blk >> 10, i0 = (blk & 1023) * ROWS;
    const size_t rowbase = (size_t)b * N_ + i0;
    {
        const int r = t >> 6, cc = (t & 63) * 4;
        const float4 gv = *(const float4*)(g + (rowbase + r) * C_ + cc);
        *(float4*)(out + (rowbase + r) * (2 * C_) + C_ + cc) = gv;
    }
    { const int r = t >> 6, d = t & 63; s_pg[r][d] = pg[(rowbase + r) * D_ + d]; }
    __syncthreads();
    const float* qb = xq + (size_t)b * N_ * D_;
    float lmax[ROWS];
#pragma unroll
    for (int r = 0; r < ROWS; ++r) lmax[r] = -1e30f;
    for (int jj = 0; jj < N_ / FNT; ++jj) {
        const int j = t + jj * FNT;
        const float4* q4p = (const float4*)(qb + (size_t)j * D_);
        float s[ROWS] = {0.f, 0.f, 0.f, 0.f};
#pragma unroll
        for (int u = 0; u < D_ / 8; ++u) {
            const float4 qa = q4p[u * 2], qc = q4p[u * 2 + 1];
#pragma unroll
            for (int r = 0; r < ROWS; ++r) {
                const float4 pa = *(const float4*)&s_pg[r][u * 8];
                const float4 pb = *(const float4*)&s_pg[r][u * 8 + 4];
                s[r] += qa.x * pa.x + qa.y * pa.y + qa.z * pa.z + qa.w * pa.w
                      + qc.x * pb.x + qc.y * pb.y + qc.z * pb.z + qc.w * pb.w;
            }
        }
        *(float4*)&s_sc[j * ROWS] = make_float4(s[0], s[1], s[2], s[3]);
#pragma unroll
        for (int r = 0; r < ROWS; ++r) lmax[r] = fmaxf(lmax[r], s[r]);
    }
#pragma unroll
    for (int r = 0; r < ROWS; ++r) {
        float m = lmax[r];
        for (int o = 32; o > 0; o >>= 1) m = fmaxf(m, __shfl_down(m, o));
        if (lane == 0) s_rmax[w][r] = m;
    }
    __syncthreads();
    float bmax[ROWS];
#pragma unroll
    for (int r = 0; r < ROWS; ++r)
        bmax[r] = fmaxf(fmaxf(s_rmax[0][r], s_rmax[1][r]), fmaxf(s_rmax[2][r], s_rmax[3][r]));
    float lsum[ROWS] = {0.f, 0.f, 0.f, 0.f};
    for (int jj = 0; jj < N_ / FNT; ++jj) {
        const int j = t + jj * FNT;
        float4 s4 = *(const float4*)&s_sc[j * ROWS];
        s4.x = __expf(s4.x - bmax[0]); s4.y = __expf(s4.y - bmax[1]);
        s4.z = __expf(s4.z - bmax[2]); s4.w = __expf(s4.w - bmax[3]);
        *(float4*)&s_sc[j * ROWS] = s4;
        lsum[0] += s4.x; lsum[1] += s4.y; lsum[2] += s4.z; lsum[3] += s4.w;
    }
#pragma unroll
    for (int r = 0; r < ROWS; ++r) {
        float sm = lsum[r];
        for (int o = 32; o > 0; o >>= 1) sm += __shfl_down(sm, o);
        if (lane == 0) s_rsum[w][r] = sm;
    }
    __syncthreads();
    float rinv[ROWS];
#pragma unroll
    for (int r = 0; r < ROWS; ++r)
        rinv[r] = 1.f / (s_rsum[0][r] + s_rsum[1][r] + s_rsum[2][r] + s_rsum[3][r]);
    const int jg = lane >> 4;
    const int c0 = (w * 16 + (lane & 15)) * 4;
    const float* vb = xv + (size_t)b * N_ * C_;
    float acc[ROWS][4];
#pragma unroll
    for (int r = 0; r < ROWS; ++r)
#pragma unroll
        for (int q = 0; q < 4; ++q) acc[r][q] = 0.f;
#pragma unroll 4
    for (int jj = 0; jj < N_ / 4; ++jj) {
        const int j = jj * 4 + jg;
        const float4 p4 = *(const float4*)&s_sc[j * ROWS];
        const float4 v4 = *(const float4*)(vb + (size_t)j * C_ + c0);
        acc[0][0] += p4.x * v4.x; acc[0][1] += p4.x * v4.y; acc[0][2] += p4.x * v4.z; acc[0][3] += p4.x * v4.w;
        acc[1][0] += p4.y * v4.x; acc[1][1] += p4.y * v4.y; acc[1][2] += p4.y * v4.z; acc[1][3] += p4.y * v4.w;
        acc[2][0] += p4.z * v4.x; acc[2][1] += p4.z * v4.y; acc[2][2] += p4.z * v4.z; acc[2][3] += p4.z * v4.w;
        acc[3][0] += p4.w * v4.x; acc[3][1] += p4.w * v4.y; acc[3][2] += p4.w * v4.z; acc[3][3] += p4.w * v4.w;
    }
#pragma unroll
    for (int r = 0; r < ROWS; ++r)
#pragma unroll
        for (int q = 0; q < 4; ++q) {
            acc[r][q] += __shfl_xor(acc[r][q], 16);
            acc[r][q] += __shfl_xor(acc[r][q], 32);
        }
    const float kval = kk[0];
    if (lane < 16) {
        const int c = (w * 16 + lane) * 4;
#pragma unroll
        for (int r = 0; r < ROWS; ++r) {
            const float4 xv4 = *(const float4*)(x + (rowbase + r) * C_ + c);
            float4 ov;
            ov.x = kval * (acc[r][0] * rinv[r]) + xv4.x;
            ov.y = kval * (acc[r][1] * rinv[r]) + xv4.y;
            ov.z = kval * (acc[r][2] * rinv[r]) + xv4.z;
            ov.w = kval * (acc[r][3] * rinv[r]) + xv4.w;
            *(float4*)(out + (rowbase + r) * (2 * C_) + c) = ov;
        }
    }
}

extern "C" void kernel_launch(void* const* d_in, const int* in_sizes, int n_in,
                              void* d_out, int out_size, void* d_ws, size_t ws_size,
                              hipStream_t stream) {
    const float* g  = (const float*)d_in[0];
    const float* x  = (const float*)d_in[1];
    const float* xq = (const float*)d_in[2];
    const float* pg = (const float*)d_in[3];
    const float* xv = (const float*)d_in[4];
    const float* kk = (const float*)d_in[5];
    float* out = (float*)d_out;

    const int B = in_sizes[0] / (N_ * C_);   // 4
    const size_t qn = (size_t)B * N_ * D_;
    const size_t vn = (size_t)B * N_ * C_;
    const size_t need = (2 * qn + vn) * sizeof(unsigned short);

    if (B != 4 || ws_size < need) {
        attn_fallback<<<dim3(B * (N_ / ROWS)), FNT, 0, stream>>>(g, x, xq, pg, xv, kk, out);
        return;
    }

    unsigned short* qbf  = (unsigned short*)d_ws;
    unsigned short* pgbf = qbf + qn;
    unsigned short* vt2  = pgbf + qn;

    prepass_kernel<<<dim3(512 + B * 128), 256, 0, stream>>>(xq, pg, xv, qbf, pgbf, vt2);
    attn_main<<<dim3(B * (N_ / 64)), 512, 0, stream>>>(g, x, kk, out, qbf, pgbf, vt2);
}

// Round 9
// 151.977 us; speedup vs baseline: 1.1602x; 1.0104x over previous
//
#include <hip/hip_runtime.h>

#define N_  4096
#define D_  64
#define C_  256

typedef short bf16x8 __attribute__((ext_vector_type(8)));
typedef float f32x4  __attribute__((ext_vector_type(4)));

// Barrier that drains only LDS ops (cross-wave P-tile hazard) but leaves
// global loads (per-wave register dests: vf/qf prefetches) in flight across
// the barrier. __syncthreads() would force vmcnt(0) and serialize L2 latency
// onto the critical path every jt (m97 stall). Compiler still inserts
// dataflow vmcnt(N) before first use of each loaded frag.
#define CHEAP_BARRIER() asm volatile("s_waitcnt lgkmcnt(0)\n\ts_barrier" ::: "memory")

__device__ __forceinline__ unsigned short f2bf(float f) {
    union { float f; unsigned int i; } v; v.f = f;
    unsigned int r = v.i + 0x7fffu + ((v.i >> 16) & 1u);
    return (unsigned short)(r >> 16);
}

// ---------- fused prepass ----------
// blocks [0,512): q->bf16 / pg->bf16 (coalesced float4->ushort4).
// blocks [512, 512+512): V -> vt2 in MFMA-B-frag order via LDS-staged
//   coalesced transpose (R8, verified).
__global__ void prepass_kernel(const float* __restrict__ xq,
                               const float* __restrict__ pg,
                               const float* __restrict__ xv,
                               unsigned short* __restrict__ qbf,
                               unsigned short* __restrict__ pgbf,
                               unsigned short* __restrict__ vt2) {
    const int bid = blockIdx.x;
    const int t   = threadIdx.x;
    if (bid < 512) {
        const float* src = (bid < 256) ? xq : pg;
        unsigned short* dst = (bid < 256) ? qbf : pgbf;
        const int base = (bid & 255) * 1024 + t;
#pragma unroll
        for (int it = 0; it < 4; ++it) {
            const int i = base + it * 256;
            float4 v = ((const float4*)src)[i];
            ushort4 o;
            o.x = f2bf(v.x); o.y = f2bf(v.y); o.z = f2bf(v.z); o.w = f2bf(v.w);
            ((ushort4*)dst)[i] = o;
        }
        return;
    }

    // ---- V staging path ----
    __shared__ unsigned short vs[128 * 66];   // 16896 B
    const int vb   = bid - 512;       // 0..511
    const int b    = vb >> 7;         // batch
    const int rem  = vb & 127;
    const int jt   = rem >> 2;        // 0..31
    const int cq   = rem & 3;         // 64-ch quarter
    const int lane = t & 63;
    const int w    = t >> 6;          // wave = ks
    const int l15  = lane & 15;
    const int quad = lane >> 4;

    // stage: 8 passes x (1 coalesced float4 read + 2 b32 LDS writes)
    {
        const int jr = t >> 4;                // 0..15 (row within pass)
        const int c0 = (t & 15) * 4;          // 0..60
        const float* src = xv + ((size_t)b * N_ + jt * 128 + jr) * C_ + cq * 64 + c0;
        unsigned short* dst = &vs[jr * 66 + c0];
#pragma unroll
        for (int p = 0; p < 8; ++p) {
            const float4 v4 = *(const float4*)(src + (size_t)p * 16 * C_);
            const unsigned int lo = (unsigned)f2bf(v4.x) | ((unsigned)f2bf(v4.y) << 16);
            const unsigned int hi = (unsigned)f2bf(v4.z) | ((unsigned)f2bf(v4.w) << 16);
            *(unsigned int*)(dst + p * 16 * 66)     = lo;
            *(unsigned int*)(dst + p * 16 * 66 + 2) = hi;
        }
    }
    __syncthreads();

    // emit: wave w = K-slice ks; 4 frags (cb_local 0..3)
    const int ks = w;
#pragma unroll
    for (int cb = 0; cb < 4; ++cb) {
        const unsigned short* pr = &vs[(ks * 32 + quad * 8) * 66 + cb * 16 + l15];
        const unsigned short e0 = pr[0 * 66], e1 = pr[1 * 66];
        const unsigned short e2 = pr[2 * 66], e3 = pr[3 * 66];
        const unsigned short e4 = pr[4 * 66], e5 = pr[5 * 66];
        const unsigned short e6 = pr[6 * 66], e7 = pr[7 * 66];
        uint4 o;
        o.x = (unsigned)e0 | ((unsigned)e1 << 16);
        o.y = (unsigned)e2 | ((unsigned)e3 << 16);
        o.z = (unsigned)e4 | ((unsigned)e5 << 16);
        o.w = (unsigned)e6 | ((unsigned)e7 << 16);
        const int f = ((b * 32 + jt) * 16 + (cq * 4 + cb)) * 4 + ks;
        *(uint4*)(vt2 + (size_t)f * 512 + lane * 8) = o;
    }
}

// ---------- main: 256 blocks x 512 thr (8 waves), M=64, j-tile 128 ----------
// R3/R8 structure (proven: passed twice, 116 VGPR no spill) with in-loop
// __syncthreads() replaced by CHEAP_BARRIER (lgkmcnt-only drain): the 8 vfB +
// 2 qf prefetch loads issued each phase stay in flight across the barrier
// instead of being force-drained by vmcnt(0) 32 times.
__global__ __launch_bounds__(512, 2) void attn_main(
    const float* __restrict__ g,  const float* __restrict__ x,
    const float* __restrict__ kk, float* __restrict__ out,
    const unsigned short* __restrict__ qbf,
    const unsigned short* __restrict__ pgbf,
    const unsigned short* __restrict__ vt2)
{
    __shared__ unsigned short p_lds[2][64 * 128];   // 32 KB, XOR-swizzled
    __shared__ float s_l[64];

    const int t    = threadIdx.x;
    const int lane = t & 63;
    const int w    = t >> 6;
    const int l15  = lane & 15;
    const int quad = lane >> 4;
    const int swz  = (l15 & 7) << 4;

    const int bid = blockIdx.x;
    const int b   = bid & 3;
    const int rg  = bid >> 2;
    const int i0  = rg * 64;
    const size_t rowbase = (size_t)b * N_ + i0;

    if (t < 64) s_l[t] = 0.f;

    // ---- g passthrough: 64 rows x 256 ch ----
#pragma unroll
    for (int it = 0; it < 8; ++it) {
        const int row = it * 8 + w;
        const int c4  = lane * 4;
        const float4 gv = *(const float4*)(g + (rowbase + row) * C_ + c4);
        *(float4*)(out + (rowbase + row) * (2 * C_) + C_ + c4) = gv;
    }

    // ---- pg B-frags: 4 i-tiles x 2 K-slices, persistent ----
    bf16x8 pgf[4][2];
#pragma unroll
    for (int nt = 0; nt < 4; ++nt)
#pragma unroll
        for (int ks = 0; ks < 2; ++ks)
            pgf[nt][ks] = *(const bf16x8*)(pgbf +
                (rowbase + nt * 16 + l15) * D_ + ks * 32 + quad * 8);

    f32x4 oacc[4][2];
#pragma unroll
    for (int mt = 0; mt < 4; ++mt) { oacc[mt][0] = (f32x4){0.f,0.f,0.f,0.f};
                                     oacc[mt][1] = (f32x4){0.f,0.f,0.f,0.f}; }
    float ls[4] = {0.f, 0.f, 0.f, 0.f};

    const unsigned short* qb  = qbf + (size_t)b * N_ * D_;
    const unsigned short* vtb = vt2 + (size_t)b * N_ * C_;
    unsigned short* const pb0 = &p_lds[0][0];
    unsigned short* const pb1 = &p_lds[1][0];

    auto load_q = [&](bf16x8 (&qf)[2], int jt) {
#pragma unroll
        for (int ks = 0; ks < 2; ++ks)
            qf[ks] = *(const bf16x8*)(qb +
                (size_t)(jt * 128 + w * 16 + l15) * D_ + ks * 32 + quad * 8);
    };
    auto load_v = [&](bf16x8 (&vf)[4][2], int jt) {
        const unsigned short* tbase = vtb + (size_t)jt * 32768;
#pragma unroll
        for (int ks = 0; ks < 4; ++ks)
#pragma unroll
            for (int ctl = 0; ctl < 2; ++ctl)
                vf[ks][ctl] = *(const bf16x8*)(tbase +
                    (size_t)(((w * 2 + ctl) * 4) + ks) * 512 + lane * 8);
    };
    auto s_step = [&](const bf16x8 (&qf)[2], unsigned short* pbuf) {
        f32x4 sacc[4];
#pragma unroll
        for (int nt = 0; nt < 4; ++nt) sacc[nt] = (f32x4){0.f,0.f,0.f,0.f};
#pragma unroll
        for (int ks = 0; ks < 2; ++ks)
#pragma unroll
            for (int nt = 0; nt < 4; ++nt)
                sacc[nt] = __builtin_amdgcn_mfma_f32_16x16x32_bf16(
                    qf[ks], pgf[nt][ks], sacc[nt], 0, 0, 0);
#pragma unroll
        for (int nt = 0; nt < 4; ++nt) {
            const float p0 = __expf(sacc[nt][0]);
            const float p1 = __expf(sacc[nt][1]);
            const float p2 = __expf(sacc[nt][2]);
            const float p3 = __expf(sacc[nt][3]);
            ls[nt] += (p0 + p1) + (p2 + p3);
            ushort4 pk;
            pk.x = f2bf(p0); pk.y = f2bf(p1); pk.z = f2bf(p2); pk.w = f2bf(p3);
            const int wb = ((nt * 16 + l15) * 256 + (w * 16 + quad * 4) * 2) ^ swz;
            *(ushort4*)((char*)pbuf + wb) = pk;
        }
    };
    auto pv_step = [&](const bf16x8 (&vf)[4][2], const unsigned short* pbuf) {
#pragma unroll
        for (int ks = 0; ks < 4; ++ks) {
            bf16x8 pa[4];
#pragma unroll
            for (int mt = 0; mt < 4; ++mt) {
                const int rb = ((mt * 16 + l15) * 256 + (ks * 32 + quad * 8) * 2) ^ swz;
                pa[mt] = *(const bf16x8*)((const char*)pbuf + rb);
            }
#pragma unroll
            for (int mt = 0; mt < 4; ++mt) {
                oacc[mt][0] = __builtin_amdgcn_mfma_f32_16x16x32_bf16(pa[mt], vf[ks][0], oacc[mt][0], 0, 0, 0);
                oacc[mt][1] = __builtin_amdgcn_mfma_f32_16x16x32_bf16(pa[mt], vf[ks][1], oacc[mt][1], 0, 0, 0);
            }
        }
    };

    bf16x8 qfA[2], qfB[2], vfA[4][2], vfB[4][2];

    // ---- prologue: S(0) -> buf0 ----
    load_q(qfA, 0);
    load_v(vfA, 0);
    s_step(qfA, pb0);
    load_q(qfB, 1);
    CHEAP_BARRIER();

    // ---- pipelined main loop: 2 jt per iteration ----
#pragma unroll 1
    for (int jtp = 0; jtp < 15; ++jtp) {
        const int jt0 = 2 * jtp;
        load_v(vfB, jt0 + 1);
        load_q(qfA, jt0 + 2);
        s_step(qfB, pb1);
        pv_step(vfA, pb0);
        CHEAP_BARRIER();
        load_v(vfA, jt0 + 2);
        load_q(qfB, jt0 + 3);
        s_step(qfA, pb0);
        pv_step(vfB, pb1);
        CHEAP_BARRIER();
    }
    // tail: jt=30 then jt=31
    load_v(vfB, 31);
    s_step(qfB, pb1);
    pv_step(vfA, pb0);
    CHEAP_BARRIER();
    pv_step(vfB, pb1);

    // ---- l reduction ----
#pragma unroll
    for (int nt = 0; nt < 4; ++nt) {
        float s = ls[nt];
        s += __shfl_xor(s, 16);
        s += __shfl_xor(s, 32);
        if (lane < 16) atomicAdd(&s_l[nt * 16 + lane], s);
    }
    __syncthreads();

    // ---- epilogue: wave owns all 64 rows x its 32-ch octant ----
    const float kval = kk[0];
#pragma unroll
    for (int mt = 0; mt < 4; ++mt)
#pragma unroll
        for (int r = 0; r < 4; ++r) {
            const int m = mt * 16 + quad * 4 + r;
            const float linv = 1.f / s_l[m];
            const size_t row = rowbase + m;
#pragma unroll
            for (int ctl = 0; ctl < 2; ++ctl) {
                const int c = w * 32 + ctl * 16 + l15;
                out[row * (2 * C_) + c] = kval * (oacc[mt][ctl][r] * linv) + x[row * C_ + c];
            }
        }
}

// ---------- fallback (round-2 vector kernel) if workspace too small ----------
#define ROWS 4
#define FNT  256
__global__ __launch_bounds__(FNT, 2) void attn_fallback(
    const float* __restrict__ g, const float* __restrict__ x,
    const float* __restrict__ xq, const float* __restrict__ pg,
    const float* __restrict__ xv, const float* __restrict__ kk,
    float* __restrict__ out)
{
    __shared__ __align__(16) float s_pg[ROWS][D_];
    __shared__ __align__(16) float s_sc[N_ * ROWS];
    __shared__ float s_rmax[4][ROWS];
    __shared__ float s_rsum[4][ROWS];

    const int t = threadIdx.x, lane = t & 63, w = t >> 6, blk = blockIdx.x;
    const int b = blk >> 10, i0 = (blk & 1023) * ROWS;
    const size_t rowbase = (size_t)b * N_ + i0;
    {
        const int r = t >> 6, cc = (t & 63) * 4;
        const float4 gv = *(const float4*)(g + (rowbase + r) * C_ + cc);
        *(float4*)(out + (rowbase + r) * (2 * C_) + C_ + cc) = gv;
    }
    { const int r = t >> 6, d = t & 63; s_pg[r][d] = pg[(rowbase + r) * D_ + d]; }
    __syncthreads();
    const float* qb = xq + (size_t)b * N_ * D_;
    float lmax[ROWS];
#pragma unroll
    for (int r = 0; r < ROWS; ++r) lmax[r] = -1e30f;
    for (int jj = 0; jj < N_ / FNT; ++jj) {
        const int j = t + jj * FNT;
        const float4* q4p = (const float4*)(qb + (size_t)j * D_);
        float s[ROWS] = {0.f, 0.f, 0.f, 0.f};
#pragma unroll
        for (int u = 0; u < D_ / 8; ++u) {
            const float4 qa = q4p[u * 2], qc = q4p[u * 2 + 1];
#pragma unroll
            for (int r = 0; r < ROWS; ++r) {
                const float4 pa = *(const float4*)&s_pg[r][u * 8];
                const float4 pb = *(const float4*)&s_pg[r][u * 8 + 4];
                s[r] += qa.x * pa.x + qa.y * pa.y + qa.z * pa.z + qa.w * pa.w
                      + qc.x * pb.x + qc.y * pb.y + qc.z * pb.z + qc.w * pb.w;
            }
        }
        *(float4*)&s_sc[j * ROWS] = make_float4(s[0], s[1], s[2], s[3]);
#pragma unroll
        for (int r = 0; r < ROWS; ++r) lmax[r] = fmaxf(lmax[r], s[r]);
    }
#pragma unroll
    for (int r = 0; r < ROWS; ++r) {
        float m = lmax[r];
        for (int o = 32; o > 0; o >>= 1) m = fmaxf(m, __shfl_down(m, o));
        if (lane == 0) s_rmax[w][r] = m;
    }
    __syncthreads();
    float bmax[ROWS];
#pragma unroll
    for (int r = 0; r < ROWS; ++r)
        bmax[r] = fmaxf(fmaxf(s_rmax[0][r], s_rmax[1][r]), fmaxf(s_rmax[2][r], s_rmax[3][r]));
    float lsum[ROWS] = {0.f, 0.f, 0.f, 0.f};
    for (int jj = 0; jj < N_ / FNT; ++jj) {
        const int j = t + jj * FNT;
        float4 s4 = *(const float4*)&s_sc[j * ROWS];
        s4.x = __expf(s4.x - bmax[0]); s4.y = __expf(s4.y - bmax[1]);
        s4.z = __expf(s4.z - bmax[2]); s4.w = __expf(s4.w - bmax[3]);
        *(float4*)&s_sc[j * ROWS] = s4;
        lsum[0] += s4.x; lsum[1] += s4.y; lsum[2] += s4.z; lsum[3] += s4.w;
    }
#pragma unroll
    for (int r = 0; r < ROWS; ++r) {
        float sm = lsum[r];
        for (int o = 32; o > 0; o >>= 1) sm += __shfl_down(sm, o);
        if (lane == 0) s_rsum[w][r] = sm;
    }
    __syncthreads();
    float rinv[ROWS];
#pragma unroll
    for (int r = 0; r < ROWS; ++r)
        rinv[r] = 1.f / (s_rsum[0][r] + s_rsum[1][r] + s_rsum[2][r] + s_rsum[3][r]);
    const int jg = lane >> 4;
    const int c0 = (w * 16 + (lane & 15)) * 4;
    const float* vb = xv + (size_t)b * N_ * C_;
    float acc[ROWS][4];
#pragma unroll
    for (int r = 0; r < ROWS; ++r)
#pragma unroll
        for (int q = 0; q < 4; ++q) acc[r][q] = 0.f;
#pragma unroll 4
    for (int jj = 0; jj < N_ / 4; ++jj) {
        const int j = jj * 4 + jg;
        const float4 p4 = *(const float4*)&s_sc[j * ROWS];
        const float4 v4 = *(const float4*)(vb + (size_t)j * C_ + c0);
        acc[0][0] += p4.x * v4.x; acc[0][1] += p4.x * v4.y; acc[0][2] += p4.x * v4.z; acc[0][3] += p4.x * v4.w;
        acc[1][0] += p4.y * v4.x; acc[1][1] += p4.y * v4.y; acc[1][2] += p4.y * v4.z; acc[1][3] += p4.y * v4.w;
        acc[2][0] += p4.z * v4.x; acc[2][1] += p4.z * v4.y; acc[2][2] += p4.z * v4.z; acc[2][3] += p4.z * v4.w;
        acc[3][0] += p4.w * v4.x; acc[3][1] += p4.w * v4.y; acc[3][2] += p4.w * v4.z; acc[3][3] += p4.w * v4.w;
    }
#pragma unroll
    for (int r = 0; r < ROWS; ++r)
#pragma unroll
        for (int q = 0; q < 4; ++q) {
            acc[r][q] += __shfl_xor(acc[r][q], 16);
            acc[r][q] += __shfl_xor(acc[r][q], 32);
        }
    const float kval = kk[0];
    if (lane < 16) {
        const int c = (w * 16 + lane) * 4;
#pragma unroll
        for (int r = 0; r < ROWS; ++r) {
            const float4 xv4 = *(const float4*)(x + (rowbase + r) * C_ + c);
            float4 ov;
            ov.x = kval * (acc[r][0] * rinv[r]) + xv4.x;
            ov.y = kval * (acc[r][1] * rinv[r]) + xv4.y;
            ov.z = kval * (acc[r][2] * rinv[r]) + xv4.z;
            ov.w = kval * (acc[r][3] * rinv[r]) + xv4.w;
            *(float4*)(out + (rowbase + r) * (2 * C_) + c) = ov;
        }
    }
}

extern "C" void kernel_launch(void* const* d_in, const int* in_sizes, int n_in,
                              void* d_out, int out_size, void* d_ws, size_t ws_size,
                              hipStream_t stream) {
    const float* g  = (const float*)d_in[0];
    const float* x  = (const float*)d_in[1];
    const float* xq = (const float*)d_in[2];
    const float* pg = (const float*)d_in[3];
    const float* xv = (const float*)d_in[4];
    const float* kk = (const float*)d_in[5];
    float* out = (float*)d_out;

    const int B = in_sizes[0] / (N_ * C_);   // 4
    const size_t qn = (size_t)B * N_ * D_;
    const size_t vn = (size_t)B * N_ * C_;
    const size_t need = (2 * qn + vn) * sizeof(unsigned short);

    if (B != 4 || ws_size < need) {
        attn_fallback<<<dim3(B * (N_ / ROWS)), FNT, 0, stream>>>(g, x, xq, pg, xv, kk, out);
        return;
    }

    unsigned short* qbf  = (unsigned short*)d_ws;
    unsigned short* pgbf = qbf + qn;
    unsigned short* vt2  = pgbf + qn;

    prepass_kernel<<<dim3(512 + B * 128), 256, 0, stream>>>(xq, pg, xv, qbf, pgbf, vt2);
    attn_main<<<dim3(B * (N_ / 64)), 512, 0, stream>>>(g, x, kk, out, qbf, pgbf, vt2);
}